// Round 1
// baseline (2891.162 us; speedup 1.0000x reference)
//
#include <hip/hip_runtime.h>

#define KN 100000
#define KE 1600000
#define KD 128

// ---------------- ws layout ----------------
// accum : KN*KD floats (51.2 MB)
// counts: KN ints      (0.4 MB)
// WT    : 256*128 floats (128 KB), k-major concat of [W_self | W_neigh]^T

__global__ void count_kernel(const int* __restrict__ src, int* __restrict__ counts) {
    int e = blockIdx.x * 256 + threadIdx.x;  // grid sized exactly
    atomicAdd(&counts[src[e]], 1);
}

// 32 threads per edge, float4 per thread: gather us[dst] row, atomic-add into accum[src]
__global__ void scatter_kernel(const float* __restrict__ us,
                               const int* __restrict__ src,
                               const int* __restrict__ dst,
                               float* __restrict__ accum) {
    unsigned long long wi = (unsigned long long)blockIdx.x * 256ull + threadIdx.x;
    int e = (int)(wi >> 5);
    int q = (int)(wi & 31);
    int s = src[e];
    int d = dst[e];
    float4 v = *reinterpret_cast<const float4*>(us + (size_t)d * KD + q * 4);
    float* a = accum + (size_t)s * KD + q * 4;
    atomicAdd(a + 0, v.x);
    atomicAdd(a + 1, v.y);
    atomicAdd(a + 2, v.z);
    atomicAdd(a + 3, v.w);
}

// WT[k][j]: k<128 -> W_self[j][k], else W_neigh[j][k-128]
__global__ void wt_kernel(const float* __restrict__ Ws, const float* __restrict__ Wn,
                          float* __restrict__ WT) {
    int tt = blockIdx.x * 256 + threadIdx.x;  // 0..32767
    int k = tt >> 7;
    int j = tt & 127;
    WT[tt] = (k < KD) ? Ws[j * KD + k] : Wn[j * KD + (k - KD)];
}

// out[n][j] = relu( sum_k<128 us[n][k]*WT[k][j] + sum accum[n][k]*rc[n]*WT[128+k][j]
//                   + b_self[j] + (cnt>0)*b_neigh[j] )
// Block: 256 thr, tile 64 nodes x 128 j. Thread: j0=(t&31)*4 (4 consecutive j),
// node group ng=t>>5 (8 nodes). K staged in LDS chunks of 64.
__launch_bounds__(256, 2)
__global__ void gemm_kernel(const float* __restrict__ us,
                            const float* __restrict__ accum,
                            const int* __restrict__ counts,
                            const float* __restrict__ WT,
                            const float* __restrict__ b_self,
                            const float* __restrict__ b_neigh,
                            float* __restrict__ out) {
    __shared__ float xs[64][64];
    __shared__ float rc_s[64];
    __shared__ float fl_s[64];

    const int t = threadIdx.x;
    const int n0 = blockIdx.x * 64;

    if (t < 64) {
        int n = n0 + t;
        int c = (n < KN) ? counts[n] : 0;
        rc_s[t] = (c > 0) ? (1.0f / (float)c) : 0.0f;
        fl_s[t] = (c > 0) ? 1.0f : 0.0f;
    }
    __syncthreads();

    const int j0 = (t & 31) * 4;
    const int ng = t >> 5;

    float acc[8][4];
#pragma unroll
    for (int g = 0; g < 8; ++g)
#pragma unroll
        for (int jj = 0; jj < 4; ++jj) acc[g][jj] = 0.0f;

    for (int kc = 0; kc < 256; kc += 64) {
        // ---- stage X chunk [64 nodes][64 k] ----
#pragma unroll
        for (int p = 0; p < 4; ++p) {
            int f4 = t + p * 256;        // 0..1023 float4 slots
            int nl = f4 >> 4;            // node-local
            int kk4 = (f4 & 15) << 2;    // k-local float4 base
            int n = n0 + nl;
            int nn = (n < KN) ? n : (KN - 1);
            float4 v;
            if (kc < 128) {
                v = *reinterpret_cast<const float4*>(us + (size_t)nn * KD + kc + kk4);
            } else {
                v = *reinterpret_cast<const float4*>(accum + (size_t)nn * KD + (kc - 128) + kk4);
                float r = rc_s[nl];
                v.x *= r; v.y *= r; v.z *= r; v.w *= r;
            }
            *reinterpret_cast<float4*>(&xs[nl][kk4]) = v;
        }
        __syncthreads();

        const float* wrow = WT + (size_t)kc * KD + j0;
#pragma unroll 4
        for (int kk = 0; kk < 64; kk += 4) {
            float4 w0 = *reinterpret_cast<const float4*>(wrow + (size_t)(kk + 0) * KD);
            float4 w1 = *reinterpret_cast<const float4*>(wrow + (size_t)(kk + 1) * KD);
            float4 w2 = *reinterpret_cast<const float4*>(wrow + (size_t)(kk + 2) * KD);
            float4 w3 = *reinterpret_cast<const float4*>(wrow + (size_t)(kk + 3) * KD);
#pragma unroll
            for (int g = 0; g < 8; ++g) {
                float4 x = *reinterpret_cast<const float4*>(&xs[ng * 8 + g][kk]);
                acc[g][0] += x.x * w0.x + x.y * w1.x + x.z * w2.x + x.w * w3.x;
                acc[g][1] += x.x * w0.y + x.y * w1.y + x.z * w2.y + x.w * w3.y;
                acc[g][2] += x.x * w0.z + x.y * w1.z + x.z * w2.z + x.w * w3.z;
                acc[g][3] += x.x * w0.w + x.y * w1.w + x.z * w2.w + x.w * w3.w;
            }
        }
        __syncthreads();
    }

    float4 bs = *reinterpret_cast<const float4*>(b_self + j0);
    float4 bn = *reinterpret_cast<const float4*>(b_neigh + j0);
#pragma unroll
    for (int g = 0; g < 8; ++g) {
        int nl = ng * 8 + g;
        int n = n0 + nl;
        if (n >= KN) break;
        float f = fl_s[nl];
        float4 o;
        o.x = fmaxf(acc[g][0] + bs.x + f * bn.x, 0.0f);
        o.y = fmaxf(acc[g][1] + bs.y + f * bn.y, 0.0f);
        o.z = fmaxf(acc[g][2] + bs.z + f * bn.z, 0.0f);
        o.w = fmaxf(acc[g][3] + bs.w + f * bn.w, 0.0f);
        *reinterpret_cast<float4*>(out + (size_t)n * KD + j0) = o;
    }
}

extern "C" void kernel_launch(void* const* d_in, const int* in_sizes, int n_in,
                              void* d_out, int out_size, void* d_ws, size_t ws_size,
                              hipStream_t stream) {
    const float* us     = (const float*)d_in[0];
    const int*   src    = (const int*)d_in[1];
    const int*   dst    = (const int*)d_in[2];
    const float* Wself  = (const float*)d_in[3];
    const float* bself  = (const float*)d_in[4];
    const float* Wneigh = (const float*)d_in[5];
    const float* bneigh = (const float*)d_in[6];
    float* out = (float*)d_out;

    float* accum  = (float*)d_ws;
    int*   counts = (int*)((char*)d_ws + (size_t)KN * KD * sizeof(float));
    float* WT     = (float*)((char*)counts + (size_t)KN * sizeof(int));

    // zero accum + counts (contiguous)
    hipMemsetAsync(d_ws, 0, (size_t)KN * KD * sizeof(float) + (size_t)KN * sizeof(int), stream);

    wt_kernel<<<128, 256, 0, stream>>>(Wself, Wneigh, WT);
    count_kernel<<<KE / 256, 256, 0, stream>>>(src, counts);
    scatter_kernel<<<(KE / 256) * 32, 256, 0, stream>>>(us, src, dst, accum);
    gemm_kernel<<<(KN + 63) / 64, 256, 0, stream>>>(us, accum, counts, WT, bself, bneigh, out);
}

// Round 2
// 414.623 us; speedup vs baseline: 6.9730x; 6.9730x over previous
//
#include <hip/hip_runtime.h>

#define KN 100000
#define KE 1600000
#define KD 128
#define NB ((KN + 255) / 256)  // 391 scan blocks

// ---------------- ws layout (bytes) ----------------
// accum     @ 0          : KN*KD f32  (51.2 MB)  -- neighbor MEAN per node
// counts    @ 51200000   : KN i32
// cursor    @ 51600000   : KN i32
// offsets   @ 52000000   : (KN+1) i32
// bsum      @ 52400128   : 512 i32
// sorted_dst@ 52402176   : KE i32    (6.4 MB)
// WT        @ 58802176   : 256*128 f32 (k-major [W_self|W_neigh]^T)

__global__ void count_kernel(const int* __restrict__ src, int* __restrict__ counts) {
    int e = blockIdx.x * 256 + threadIdx.x;  // grid sized exactly KE/256
    atomicAdd(&counts[src[e]], 1);
}

__global__ void scan1_kernel(const int* __restrict__ counts, int* __restrict__ offsets,
                             int* __restrict__ bsum) {
    __shared__ int s[256];
    int t = threadIdx.x, b = blockIdx.x;
    int i = b * 256 + t;
    int v = (i < KN) ? counts[i] : 0;
    s[t] = v;
    __syncthreads();
    for (int off = 1; off < 256; off <<= 1) {
        int x = (t >= off) ? s[t - off] : 0;
        __syncthreads();
        s[t] += x;
        __syncthreads();
    }
    if (i < KN) offsets[i] = s[t] - v;  // exclusive
    if (t == 255) bsum[b] = s[t];
}

__global__ void scan2_kernel(int* __restrict__ bsum) {
    __shared__ int s[512];
    int t = threadIdx.x;
    int v = (t < NB) ? bsum[t] : 0;
    s[t] = v;
    __syncthreads();
    for (int off = 1; off < 512; off <<= 1) {
        int x = (t >= off) ? s[t - off] : 0;
        __syncthreads();
        s[t] += x;
        __syncthreads();
    }
    bsum[t] = s[t] - v;  // exclusive block offsets
}

__global__ void scan3_kernel(int* __restrict__ offsets, const int* __restrict__ bsum) {
    int t = threadIdx.x, b = blockIdx.x;
    int i = b * 256 + t;
    if (i < KN) offsets[i] += bsum[b];
    if (i == 0) offsets[KN] = KE;
}

__global__ void fill_kernel(const int* __restrict__ src, const int* __restrict__ dst,
                            const int* __restrict__ offsets, int* __restrict__ cursor,
                            int* __restrict__ sorted_dst) {
    int e = blockIdx.x * 256 + threadIdx.x;
    int s = src[e];
    int p = offsets[s] + atomicAdd(&cursor[s], 1);
    sorted_dst[p] = dst[e];
}

// One wave per node. Lane owns a float2 slice of the 128-float row.
// Edge indices fetched 64-at-a-time, broadcast with __shfl.
__launch_bounds__(256)
__global__ void aggregate_kernel(const float* __restrict__ us,
                                 const int* __restrict__ offsets,
                                 const int* __restrict__ sorted_dst,
                                 float* __restrict__ accum) {
    int wave = (int)((blockIdx.x * 256 + threadIdx.x) >> 6);
    int lane = threadIdx.x & 63;
    if (wave >= KN) return;
    int ofs = offsets[wave], end = offsets[wave + 1];
    float ax = 0.f, ay = 0.f;
    for (int base = ofs; base < end; base += 64) {
        int m = end - base;
        if (m > 64) m = 64;
        int myi = (lane < m) ? sorted_dst[base + lane] : 0;
        for (int j = 0; j < m; ++j) {
            int d = __shfl(myi, j);
            float2 v = *reinterpret_cast<const float2*>(us + (size_t)d * KD + lane * 2);
            ax += v.x;
            ay += v.y;
        }
    }
    int c = end - ofs;
    float rc = (c > 0) ? 1.0f / (float)c : 0.0f;
    float2 o;
    o.x = ax * rc;
    o.y = ay * rc;
    *reinterpret_cast<float2*>(accum + (size_t)wave * KD + lane * 2) = o;
}

// WT[k][j]: k<128 -> W_self[j][k], else W_neigh[j][k-128]
__global__ void wt_kernel(const float* __restrict__ Ws, const float* __restrict__ Wn,
                          float* __restrict__ WT) {
    int tt = blockIdx.x * 256 + threadIdx.x;  // 0..32767
    int k = tt >> 7;
    int j = tt & 127;
    WT[tt] = (k < KD) ? Ws[j * KD + k] : Wn[j * KD + (k - KD)];
}

// out[n][j] = relu( [us[n] | mean[n]] @ WT + b_self[j] + (cnt>0)*b_neigh[j] )
__launch_bounds__(256, 2)
__global__ void gemm_kernel(const float* __restrict__ us,
                            const float* __restrict__ accum,
                            const int* __restrict__ counts,
                            const float* __restrict__ WT,
                            const float* __restrict__ b_self,
                            const float* __restrict__ b_neigh,
                            float* __restrict__ out) {
    __shared__ float xs[64][64];
    __shared__ float fl_s[64];

    const int t = threadIdx.x;
    const int n0 = blockIdx.x * 64;

    if (t < 64) {
        int n = n0 + t;
        int c = (n < KN) ? counts[n] : 0;
        fl_s[t] = (c > 0) ? 1.0f : 0.0f;
    }
    __syncthreads();

    const int j0 = (t & 31) * 4;
    const int ng = t >> 5;

    float acc[8][4];
#pragma unroll
    for (int g = 0; g < 8; ++g)
#pragma unroll
        for (int jj = 0; jj < 4; ++jj) acc[g][jj] = 0.0f;

    for (int kc = 0; kc < 256; kc += 64) {
        // ---- stage X chunk [64 nodes][64 k] ----
#pragma unroll
        for (int p = 0; p < 4; ++p) {
            int f4 = t + p * 256;      // 0..1023 float4 slots
            int nl = f4 >> 4;          // node-local
            int kk4 = (f4 & 15) << 2;  // k-local float4 base
            int n = n0 + nl;
            int nn = (n < KN) ? n : (KN - 1);
            float4 v;
            if (kc < 128) {
                v = *reinterpret_cast<const float4*>(us + (size_t)nn * KD + kc + kk4);
            } else {
                v = *reinterpret_cast<const float4*>(accum + (size_t)nn * KD + (kc - 128) + kk4);
            }
            *reinterpret_cast<float4*>(&xs[nl][kk4]) = v;
        }
        __syncthreads();

        const float* wrow = WT + (size_t)kc * KD + j0;
#pragma unroll 4
        for (int kk = 0; kk < 64; kk += 4) {
            float4 w0 = *reinterpret_cast<const float4*>(wrow + (size_t)(kk + 0) * KD);
            float4 w1 = *reinterpret_cast<const float4*>(wrow + (size_t)(kk + 1) * KD);
            float4 w2 = *reinterpret_cast<const float4*>(wrow + (size_t)(kk + 2) * KD);
            float4 w3 = *reinterpret_cast<const float4*>(wrow + (size_t)(kk + 3) * KD);
#pragma unroll
            for (int g = 0; g < 8; ++g) {
                float4 x = *reinterpret_cast<const float4*>(&xs[ng * 8 + g][kk]);
                acc[g][0] += x.x * w0.x + x.y * w1.x + x.z * w2.x + x.w * w3.x;
                acc[g][1] += x.x * w0.y + x.y * w1.y + x.z * w2.y + x.w * w3.y;
                acc[g][2] += x.x * w0.z + x.y * w1.z + x.z * w2.z + x.w * w3.z;
                acc[g][3] += x.x * w0.w + x.y * w1.w + x.z * w2.w + x.w * w3.w;
            }
        }
        __syncthreads();
    }

    float4 bs = *reinterpret_cast<const float4*>(b_self + j0);
    float4 bn = *reinterpret_cast<const float4*>(b_neigh + j0);
#pragma unroll
    for (int g = 0; g < 8; ++g) {
        int nl = ng * 8 + g;
        int n = n0 + nl;
        if (n >= KN) break;
        float f = fl_s[nl];
        float4 o;
        o.x = fmaxf(acc[g][0] + bs.x + f * bn.x, 0.0f);
        o.y = fmaxf(acc[g][1] + bs.y + f * bn.y, 0.0f);
        o.z = fmaxf(acc[g][2] + bs.z + f * bn.z, 0.0f);
        o.w = fmaxf(acc[g][3] + bs.w + f * bn.w, 0.0f);
        *reinterpret_cast<float4*>(out + (size_t)n * KD + j0) = o;
    }
}

extern "C" void kernel_launch(void* const* d_in, const int* in_sizes, int n_in,
                              void* d_out, int out_size, void* d_ws, size_t ws_size,
                              hipStream_t stream) {
    const float* us     = (const float*)d_in[0];
    const int*   src    = (const int*)d_in[1];
    const int*   dst    = (const int*)d_in[2];
    const float* Wself  = (const float*)d_in[3];
    const float* bself  = (const float*)d_in[4];
    const float* Wneigh = (const float*)d_in[5];
    const float* bneigh = (const float*)d_in[6];
    float* out = (float*)d_out;

    char* ws = (char*)d_ws;
    float* accum      = (float*)(ws + 0);
    int*   counts     = (int*)(ws + 51200000);
    int*   cursor     = (int*)(ws + 51600000);
    int*   offsets    = (int*)(ws + 52000000);
    int*   bsum       = (int*)(ws + 52400128);
    int*   sorted_dst = (int*)(ws + 52402176);
    float* WT         = (float*)(ws + 58802176);

    // zero counts + cursor (contiguous 0.8 MB)
    hipMemsetAsync(counts, 0, 2 * (size_t)KN * sizeof(int), stream);

    wt_kernel<<<128, 256, 0, stream>>>(Wself, Wneigh, WT);
    count_kernel<<<KE / 256, 256, 0, stream>>>(src, counts);
    scan1_kernel<<<NB, 256, 0, stream>>>(counts, offsets, bsum);
    scan2_kernel<<<1, 512, 0, stream>>>(bsum);
    scan3_kernel<<<NB, 256, 0, stream>>>(offsets, bsum);
    fill_kernel<<<KE / 256, 256, 0, stream>>>(src, dst, offsets, cursor, sorted_dst);
    aggregate_kernel<<<(KN * 64 + 255) / 256, 256, 0, stream>>>(us, offsets, sorted_dst, accum);
    gemm_kernel<<<(KN + 63) / 64, 256, 0, stream>>>(us, accum, counts, WT, bself, bneigh, out);
}

// Round 3
// 333.500 us; speedup vs baseline: 8.6692x; 1.2432x over previous
//
#include <hip/hip_runtime.h>

#define KN 100000
#define KE 1600000
#define KD 128
#define NB ((KN + 255) / 256)  // 391 scan blocks

typedef __bf16 bf16;
typedef __attribute__((ext_vector_type(8))) __bf16 bf16x8;
typedef __attribute__((ext_vector_type(4))) __bf16 bf16x4;
typedef __attribute__((ext_vector_type(2))) __bf16 bf16x2;
typedef __attribute__((ext_vector_type(4))) float f32x4;

// ---------------- ws layout (bytes) ----------------
// meanb     @ 0          : KN*128 bf16 (25.6 MB)  -- neighbor MEAN per node
// usb       @ 25600000   : KN*128 bf16 (25.6 MB)  -- user_states in bf16
// counts    @ 51200000   : KN i32
// cursor    @ 51600000   : KN i32
// offsets   @ 52000000   : (KN+1) i32
// bsum      @ 52400128   : 512 i32
// sorted_dst@ 52402176   : KE i32 (6.4 MB)
// Wb        @ 58802176   : 128*256 bf16 (64 KB), j-major: Wb[j][k] = [W_self|W_neigh][j][k]

__global__ void convert_kernel(const float* __restrict__ us, bf16* __restrict__ usb) {
    int i = blockIdx.x * 256 + threadIdx.x;  // grid exact: 12.8M/4 elems
    float4 v = reinterpret_cast<const float4*>(us)[i];
    bf16x4 o = {(bf16)v.x, (bf16)v.y, (bf16)v.z, (bf16)v.w};
    reinterpret_cast<bf16x4*>(usb)[i] = o;
}

__global__ void wt_kernel(const float* __restrict__ Ws, const float* __restrict__ Wn,
                          bf16* __restrict__ Wb) {
    int tt = blockIdx.x * 256 + threadIdx.x;  // 0..32767
    int j = tt >> 8;
    int k = tt & 255;
    float v = (k < KD) ? Ws[j * KD + k] : Wn[j * KD + (k - KD)];
    Wb[tt] = (bf16)v;
}

__global__ void count_kernel(const int* __restrict__ src, int* __restrict__ counts) {
    int e = blockIdx.x * 256 + threadIdx.x;
    atomicAdd(&counts[src[e]], 1);
}

__global__ void scan1_kernel(const int* __restrict__ counts, int* __restrict__ offsets,
                             int* __restrict__ bsum) {
    __shared__ int s[256];
    int t = threadIdx.x, b = blockIdx.x;
    int i = b * 256 + t;
    int v = (i < KN) ? counts[i] : 0;
    s[t] = v;
    __syncthreads();
    for (int off = 1; off < 256; off <<= 1) {
        int x = (t >= off) ? s[t - off] : 0;
        __syncthreads();
        s[t] += x;
        __syncthreads();
    }
    if (i < KN) offsets[i] = s[t] - v;  // exclusive
    if (t == 255) bsum[b] = s[t];
}

__global__ void scan2_kernel(int* __restrict__ bsum) {
    __shared__ int s[512];
    int t = threadIdx.x;
    int v = (t < NB) ? bsum[t] : 0;
    s[t] = v;
    __syncthreads();
    for (int off = 1; off < 512; off <<= 1) {
        int x = (t >= off) ? s[t - off] : 0;
        __syncthreads();
        s[t] += x;
        __syncthreads();
    }
    bsum[t] = s[t] - v;
}

__global__ void scan3_kernel(int* __restrict__ offsets, const int* __restrict__ bsum) {
    int t = threadIdx.x, b = blockIdx.x;
    int i = b * 256 + t;
    if (i < KN) offsets[i] += bsum[b];
    if (i == 0) offsets[KN] = KE;
}

__global__ void fill_kernel(const int* __restrict__ src, const int* __restrict__ dst,
                            const int* __restrict__ offsets, int* __restrict__ cursor,
                            int* __restrict__ sorted_dst) {
    int e = blockIdx.x * 256 + threadIdx.x;
    int s = src[e];
    int p = offsets[s] + atomicAdd(&cursor[s], 1);
    sorted_dst[p] = dst[e];
}

// One wave per node; lane owns 2 bf16 (4B) of the 128-col row.
__launch_bounds__(256)
__global__ void aggregate_kernel(const bf16* __restrict__ usb,
                                 const int* __restrict__ offsets,
                                 const int* __restrict__ sorted_dst,
                                 bf16* __restrict__ meanb) {
    int wave = (int)((blockIdx.x * 256 + threadIdx.x) >> 6);
    int lane = threadIdx.x & 63;
    if (wave >= KN) return;
    int ofs = offsets[wave], end = offsets[wave + 1];
    float ax = 0.f, ay = 0.f;
    for (int base = ofs; base < end; base += 64) {
        int m = end - base;
        if (m > 64) m = 64;
        int myi = (lane < m) ? sorted_dst[base + lane] : 0;
        for (int j = 0; j < m; ++j) {
            int d = __shfl(myi, j);
            bf16x2 v = *reinterpret_cast<const bf16x2*>(usb + (size_t)d * KD + lane * 2);
            ax += (float)v[0];
            ay += (float)v[1];
        }
    }
    int c = end - ofs;
    float rc = (c > 0) ? 1.0f / (float)c : 0.0f;
    bf16x2 o = {(bf16)(ax * rc), (bf16)(ay * rc)};
    *reinterpret_cast<bf16x2*>(meanb + (size_t)wave * KD + lane * 2) = o;
}

// MFMA GEMM: out[n][j] = relu( X[n]·Wcat[j] + b_self[j] + fl[n]*b_neigh[j] )
// X = [usb | meanb] (K=256). Block = 4 waves, 64 rows x 128 cols.
// Wave w owns cols [32w, 32w+32): 2 col-tiles of 16. 4 row-tiles of 16.
// k-mapping: frag elem (g=lane>>4, i) <-> k = g*8+i for BOTH A and B (bijection
// cancels against HW's internal k layout). A row = lane&15; B col = lane&15;
// D: col = lane&15, row = (lane>>4)*4 + reg  [verified m89/m91].
__launch_bounds__(256, 3)
__global__ void gemm_kernel(const bf16* __restrict__ usb, const bf16* __restrict__ meanb,
                            const int* __restrict__ offsets, const bf16* __restrict__ Wb,
                            const float* __restrict__ b_self, const float* __restrict__ b_neigh,
                            float* __restrict__ out) {
    __shared__ bf16 xs[64][264];  // 264 = 256 + 8 pad -> row stride 528B, balanced banks
    __shared__ float fl_s[64];

    const int t = threadIdx.x;
    const int n0 = blockIdx.x * 64;
    const int lane = t & 63;
    const int w = t >> 6;
    const int lr = lane & 15;  // row (A) / col (B,D) within tile
    const int g = lane >> 4;   // k-group

    if (t < 64) {
        int n = n0 + t;
        int c = (n < KN) ? (offsets[n + 1] - offsets[n]) : 0;
        fl_s[t] = (c > 0) ? 1.0f : 0.0f;
    }

    // B fragments resident in VGPRs: 2 col-tiles x 8 k-chunks
    bf16x8 Bf[2][8];
    const int colb = w * 32;
#pragma unroll
    for (int ct = 0; ct < 2; ++ct) {
        const bf16* wp = Wb + (size_t)(colb + ct * 16 + lr) * 256 + g * 8;
#pragma unroll
        for (int ch = 0; ch < 8; ++ch) Bf[ct][ch] = *reinterpret_cast<const bf16x8*>(wp + ch * 32);
    }

    // stage X tile: 64 rows x 256 k (bf16), coalesced 16B chunks
#pragma unroll
    for (int p = 0; p < 8; ++p) {
        int c = t + p * 256;     // 0..2047 chunks of 8 bf16
        int row = c >> 5;        // 32 chunks per row
        int ko = (c & 31) * 8;   // k offset
        int n = n0 + row;
        if (n >= KN) n = KN - 1;
        const bf16* srcp = (ko < KD) ? (usb + (size_t)n * KD + ko)
                                     : (meanb + (size_t)n * KD + (ko - KD));
        *reinterpret_cast<bf16x8*>(&xs[row][ko]) = *reinterpret_cast<const bf16x8*>(srcp);
    }
    __syncthreads();

    const float bs0 = b_self[colb + lr], bn0 = b_neigh[colb + lr];
    const float bs1 = b_self[colb + 16 + lr], bn1 = b_neigh[colb + 16 + lr];

#pragma unroll
    for (int rt = 0; rt < 4; ++rt) {
        f32x4 acc0 = {0.f, 0.f, 0.f, 0.f}, acc1 = {0.f, 0.f, 0.f, 0.f};
        const bf16* ap = &xs[rt * 16 + lr][g * 8];
#pragma unroll
        for (int ch = 0; ch < 8; ++ch) {
            bf16x8 af = *reinterpret_cast<const bf16x8*>(ap + ch * 32);
            acc0 = __builtin_amdgcn_mfma_f32_16x16x32_bf16(af, Bf[0][ch], acc0, 0, 0, 0);
            acc1 = __builtin_amdgcn_mfma_f32_16x16x32_bf16(af, Bf[1][ch], acc1, 0, 0, 0);
        }
#pragma unroll
        for (int r = 0; r < 4; ++r) {
            int rl = rt * 16 + g * 4 + r;
            int n = n0 + rl;
            if (n < KN) {
                float f = fl_s[rl];
                float o0 = fmaxf(acc0[r] + bs0 + f * bn0, 0.0f);
                float o1 = fmaxf(acc1[r] + bs1 + f * bn1, 0.0f);
                out[(size_t)n * KD + colb + lr] = o0;
                out[(size_t)n * KD + colb + 16 + lr] = o1;
            }
        }
    }
}

extern "C" void kernel_launch(void* const* d_in, const int* in_sizes, int n_in,
                              void* d_out, int out_size, void* d_ws, size_t ws_size,
                              hipStream_t stream) {
    const float* us     = (const float*)d_in[0];
    const int*   src    = (const int*)d_in[1];
    const int*   dst    = (const int*)d_in[2];
    const float* Wself  = (const float*)d_in[3];
    const float* bself  = (const float*)d_in[4];
    const float* Wneigh = (const float*)d_in[5];
    const float* bneigh = (const float*)d_in[6];
    float* out = (float*)d_out;

    char* ws = (char*)d_ws;
    bf16*  meanb      = (bf16*)(ws + 0);
    bf16*  usb        = (bf16*)(ws + 25600000);
    int*   counts     = (int*)(ws + 51200000);
    int*   cursor     = (int*)(ws + 51600000);
    int*   offsets    = (int*)(ws + 52000000);
    int*   bsum       = (int*)(ws + 52400128);
    int*   sorted_dst = (int*)(ws + 52402176);
    bf16*  Wb         = (bf16*)(ws + 58802176);

    // zero counts + cursor (contiguous 0.8 MB)
    hipMemsetAsync(counts, 0, 2 * (size_t)KN * sizeof(int), stream);

    convert_kernel<<<12500, 256, 0, stream>>>(us, usb);          // 12.8M/(256*4)
    wt_kernel<<<128, 256, 0, stream>>>(Wself, Wneigh, Wb);
    count_kernel<<<KE / 256, 256, 0, stream>>>(src, counts);
    scan1_kernel<<<NB, 256, 0, stream>>>(counts, offsets, bsum);
    scan2_kernel<<<1, 512, 0, stream>>>(bsum);
    scan3_kernel<<<NB, 256, 0, stream>>>(offsets, bsum);
    fill_kernel<<<KE / 256, 256, 0, stream>>>(src, dst, offsets, cursor, sorted_dst);
    aggregate_kernel<<<(KN * 64 + 255) / 256, 256, 0, stream>>>(usb, offsets, sorted_dst, meanb);
    gemm_kernel<<<(KN + 63) / 64, 256, 0, stream>>>(usb, meanb, offsets, Wb, bself, bneigh, out);
}

// Round 4
// 137.137 us; speedup vs baseline: 21.0822x; 2.4319x over previous
//
#include <hip/hip_runtime.h>

#define KN 100000
#define KE 1600000
#define KD 128
#define NBKT 391    // node buckets of 256
#define NBLKE 391   // edge blocks of EPB
#define EPB 4096
#define SRTCAP 5120 // max edges per bucket (mean 4096, sigma 64 -> 16 sigma headroom)

typedef __bf16 bf16;
typedef __attribute__((ext_vector_type(8))) __bf16 bf16x8;
typedef __attribute__((ext_vector_type(4))) __bf16 bf16x4;
typedef __attribute__((ext_vector_type(2))) __bf16 bf16x2;
typedef __attribute__((ext_vector_type(4))) float f32x4;

// ---------------- ws layout (bytes) ----------------
// meanb   @ 0        : KN*128 bf16 (25.6 MB)
// usb     @ 25600000 : KN*128 bf16 (25.6 MB)
// counts  @ 51200000 : KN i32
// packed  @ 51600000 : KE i32 (6.4 MB)   (dst<<8 | src&255), bucket-grouped
// Hc      @ 58000000 : NBKT*NBLKE i32 (611 KB), [bucket][block]
// bktsum  @ 58700000 : NBKT i32
// bktbase @ 58710000 : (NBKT+1) i32
// Wb      @ 58720000 : 128*256 bf16 (64 KB), j-major [W_self|W_neigh]

__global__ void convert_kernel(const float* __restrict__ us, bf16* __restrict__ usb) {
    int i = blockIdx.x * 256 + threadIdx.x;  // grid exact: 12.8M/4 elems
    float4 v = reinterpret_cast<const float4*>(us)[i];
    bf16x4 o = {(bf16)v.x, (bf16)v.y, (bf16)v.z, (bf16)v.w};
    reinterpret_cast<bf16x4*>(usb)[i] = o;
}

__global__ void wt_kernel(const float* __restrict__ Ws, const float* __restrict__ Wn,
                          bf16* __restrict__ Wb) {
    int tt = blockIdx.x * 256 + threadIdx.x;  // 0..32767
    int j = tt >> 8;
    int k = tt & 255;
    float v = (k < KD) ? Ws[j * KD + k] : Wn[j * KD + (k - KD)];
    Wb[tt] = (bf16)v;
}

__global__ void histA_kernel(const int* __restrict__ src, int* __restrict__ Hc) {
    __shared__ int h[NBKT];
    int t = threadIdx.x, b = blockIdx.x;
    for (int j = t; j < NBKT; j += 256) h[j] = 0;
    __syncthreads();
    int e0 = b * EPB;
#pragma unroll
    for (int i = 0; i < EPB / 256; ++i) {
        int e = e0 + i * 256 + t;
        if (e < KE) atomicAdd(&h[src[e] >> 8], 1);
    }
    __syncthreads();
    for (int j = t; j < NBKT; j += 256) Hc[j * NBLKE + b] = h[j];
}

// scan each bucket-row of Hc over blocks; emit bucket totals
__global__ void colscan_kernel(int* __restrict__ Hc, int* __restrict__ bktsum) {
    __shared__ int s[512];
    int t = threadIdx.x, b = blockIdx.x;  // bucket b
    int v = (t < NBLKE) ? Hc[b * NBLKE + t] : 0;
    s[t] = v;
    __syncthreads();
    for (int o2 = 1; o2 < 512; o2 <<= 1) {
        int x = (t >= o2) ? s[t - o2] : 0;
        __syncthreads();
        s[t] += x;
        __syncthreads();
    }
    if (t < NBLKE) Hc[b * NBLKE + t] = s[t] - v;  // exclusive over blocks
    if (t == 511) bktsum[b] = s[511];
}

__global__ void bktscan_kernel(const int* __restrict__ bktsum, int* __restrict__ bktbase) {
    __shared__ int s[512];
    int t = threadIdx.x;
    int v = (t < NBKT) ? bktsum[t] : 0;
    s[t] = v;
    __syncthreads();
    for (int o2 = 1; o2 < 512; o2 <<= 1) {
        int x = (t >= o2) ? s[t - o2] : 0;
        __syncthreads();
        s[t] += x;
        __syncthreads();
    }
    if (t <= NBKT) bktbase[t] = s[t] - v;  // t==NBKT: v=0 -> total = KE
}

__global__ void scatA_kernel(const int* __restrict__ src, const int* __restrict__ dst,
                             const int* __restrict__ Hc, const int* __restrict__ bktbase,
                             int* __restrict__ packed) {
    __shared__ int base[NBKT];
    __shared__ int cur[NBKT];
    int t = threadIdx.x, b = blockIdx.x;
    for (int j = t; j < NBKT; j += 256) {
        base[j] = bktbase[j] + Hc[j * NBLKE + b];
        cur[j] = 0;
    }
    __syncthreads();
    int e0 = b * EPB;
#pragma unroll
    for (int i = 0; i < EPB / 256; ++i) {
        int e = e0 + i * 256 + t;
        if (e < KE) {
            int s = src[e], d = dst[e];
            int j = s >> 8;
            int r = atomicAdd(&cur[j], 1);
            packed[base[j] + r] = (d << 8) | (s & 255);
        }
    }
}

// One block per bucket: LDS counting-sort by src_low, then gather-aggregate.
__launch_bounds__(1024)
__global__ void sortagg_kernel(const bf16* __restrict__ usb, const int* __restrict__ packed,
                               const int* __restrict__ bktbase, bf16* __restrict__ meanb,
                               int* __restrict__ counts) {
    __shared__ int srt[SRTCAP];
    __shared__ int h[256], scn[256], off[256], cur[256];
    int t = threadIdx.x, b = blockIdx.x;
    int n0 = b << 8;
    int E0 = bktbase[b];
    int E = bktbase[b + 1] - E0;

    if (t < 256) { h[t] = 0; cur[t] = 0; }
    __syncthreads();
    for (int i = t; i < E; i += 1024) atomicAdd(&h[packed[E0 + i] & 255], 1);
    __syncthreads();
    if (t < 256) scn[t] = h[t];
    __syncthreads();
    for (int o2 = 1; o2 < 256; o2 <<= 1) {
        int x = 0;
        if (t < 256 && t >= o2) x = scn[t - o2];
        __syncthreads();
        if (t < 256) scn[t] += x;
        __syncthreads();
    }
    if (t < 256) {
        off[t] = scn[t] - h[t];
        int n = n0 + t;
        if (n < KN) counts[n] = h[t];
    }
    __syncthreads();
    for (int i = t; i < E; i += 1024) {
        int v = packed[E0 + i];
        int sl = v & 255;
        int r = atomicAdd(&cur[sl], 1);
        int p = off[sl] + r;
        if (p < SRTCAP) srt[p] = v >> 8;
    }
    __syncthreads();

    // aggregate: wave w owns nodes [w*16, w*16+16); 16-lane groups do 4 edges/iter
    int lane = t & 63, w = t >> 6;
    int qu = lane >> 4;  // edge slot 0..3
    int cl = lane & 15;  // owns cols cl*8 .. cl*8+7
    for (int q = 0; q < 16; ++q) {
        int nl = w * 16 + q;
        int n = n0 + nl;
        if (n >= KN) break;
        int cnt = h[nl], o = off[nl];
        float a[8];
#pragma unroll
        for (int j = 0; j < 8; ++j) a[j] = 0.0f;
        int e2 = 0;
        for (; e2 + 4 <= cnt; e2 += 4) {
            int d = srt[o + e2 + qu];
            bf16x8 vv = *reinterpret_cast<const bf16x8*>(usb + (size_t)d * KD + cl * 8);
#pragma unroll
            for (int j = 0; j < 8; ++j) a[j] += (float)vv[j];
        }
        int rem = cnt - e2;
        if (qu < rem) {
            int d = srt[o + e2 + qu];
            bf16x8 vv = *reinterpret_cast<const bf16x8*>(usb + (size_t)d * KD + cl * 8);
#pragma unroll
            for (int j = 0; j < 8; ++j) a[j] += (float)vv[j];
        }
#pragma unroll
        for (int j = 0; j < 8; ++j) {
            a[j] += __shfl_xor(a[j], 16);
            a[j] += __shfl_xor(a[j], 32);
        }
        if (qu == 0) {
            float rc = (cnt > 0) ? 1.0f / (float)cnt : 0.0f;
            bf16x8 ov;
#pragma unroll
            for (int j = 0; j < 8; ++j) ov[j] = (bf16)(a[j] * rc);
            *reinterpret_cast<bf16x8*>(meanb + (size_t)n * KD + cl * 8) = ov;
        }
    }
}

// MFMA GEMM: out[n][j] = relu( [usb|meanb][n]·Wcat[j] + b_self[j] + fl[n]*b_neigh[j] )
__launch_bounds__(256, 3)
__global__ void gemm_kernel(const bf16* __restrict__ usb, const bf16* __restrict__ meanb,
                            const int* __restrict__ counts, const bf16* __restrict__ Wb,
                            const float* __restrict__ b_self, const float* __restrict__ b_neigh,
                            float* __restrict__ out) {
    __shared__ bf16 xs[64][264];
    __shared__ float fl_s[64];

    const int t = threadIdx.x;
    const int n0 = blockIdx.x * 64;
    const int lane = t & 63;
    const int w = t >> 6;
    const int lr = lane & 15;
    const int g = lane >> 4;

    if (t < 64) {
        int n = n0 + t;
        int c = (n < KN) ? counts[n] : 0;
        fl_s[t] = (c > 0) ? 1.0f : 0.0f;
    }

    bf16x8 Bf[2][8];
    const int colb = w * 32;
#pragma unroll
    for (int ct = 0; ct < 2; ++ct) {
        const bf16* wp = Wb + (size_t)(colb + ct * 16 + lr) * 256 + g * 8;
#pragma unroll
        for (int ch = 0; ch < 8; ++ch) Bf[ct][ch] = *reinterpret_cast<const bf16x8*>(wp + ch * 32);
    }

#pragma unroll
    for (int p = 0; p < 8; ++p) {
        int c = t + p * 256;
        int row = c >> 5;
        int ko = (c & 31) * 8;
        int n = n0 + row;
        if (n >= KN) n = KN - 1;
        const bf16* srcp = (ko < KD) ? (usb + (size_t)n * KD + ko)
                                     : (meanb + (size_t)n * KD + (ko - KD));
        *reinterpret_cast<bf16x8*>(&xs[row][ko]) = *reinterpret_cast<const bf16x8*>(srcp);
    }
    __syncthreads();

    const float bs0 = b_self[colb + lr], bn0 = b_neigh[colb + lr];
    const float bs1 = b_self[colb + 16 + lr], bn1 = b_neigh[colb + 16 + lr];

#pragma unroll
    for (int rt = 0; rt < 4; ++rt) {
        f32x4 acc0 = {0.f, 0.f, 0.f, 0.f}, acc1 = {0.f, 0.f, 0.f, 0.f};
        const bf16* ap = &xs[rt * 16 + lr][g * 8];
#pragma unroll
        for (int ch = 0; ch < 8; ++ch) {
            bf16x8 af = *reinterpret_cast<const bf16x8*>(ap + ch * 32);
            acc0 = __builtin_amdgcn_mfma_f32_16x16x32_bf16(af, Bf[0][ch], acc0, 0, 0, 0);
            acc1 = __builtin_amdgcn_mfma_f32_16x16x32_bf16(af, Bf[1][ch], acc1, 0, 0, 0);
        }
#pragma unroll
        for (int r = 0; r < 4; ++r) {
            int rl = rt * 16 + g * 4 + r;
            int n = n0 + rl;
            if (n < KN) {
                float f = fl_s[rl];
                float o0 = fmaxf(acc0[r] + bs0 + f * bn0, 0.0f);
                float o1 = fmaxf(acc1[r] + bs1 + f * bn1, 0.0f);
                out[(size_t)n * KD + colb + lr] = o0;
                out[(size_t)n * KD + colb + 16 + lr] = o1;
            }
        }
    }
}

extern "C" void kernel_launch(void* const* d_in, const int* in_sizes, int n_in,
                              void* d_out, int out_size, void* d_ws, size_t ws_size,
                              hipStream_t stream) {
    const float* us     = (const float*)d_in[0];
    const int*   src    = (const int*)d_in[1];
    const int*   dst    = (const int*)d_in[2];
    const float* Wself  = (const float*)d_in[3];
    const float* bself  = (const float*)d_in[4];
    const float* Wneigh = (const float*)d_in[5];
    const float* bneigh = (const float*)d_in[6];
    float* out = (float*)d_out;

    char* ws = (char*)d_ws;
    bf16* meanb   = (bf16*)(ws + 0);
    bf16* usb     = (bf16*)(ws + 25600000);
    int*  counts  = (int*)(ws + 51200000);
    int*  packed  = (int*)(ws + 51600000);
    int*  Hc      = (int*)(ws + 58000000);
    int*  bktsum  = (int*)(ws + 58700000);
    int*  bktbase = (int*)(ws + 58710000);
    bf16* Wb      = (bf16*)(ws + 58720000);

    convert_kernel<<<12500, 256, 0, stream>>>(us, usb);
    wt_kernel<<<128, 256, 0, stream>>>(Wself, Wneigh, Wb);
    histA_kernel<<<NBLKE, 256, 0, stream>>>(src, Hc);
    colscan_kernel<<<NBKT, 512, 0, stream>>>(Hc, bktsum);
    bktscan_kernel<<<1, 512, 0, stream>>>(bktsum, bktbase);
    scatA_kernel<<<NBLKE, 256, 0, stream>>>(src, dst, Hc, bktbase, packed);
    sortagg_kernel<<<NBKT, 1024, 0, stream>>>(usb, packed, bktbase, meanb, counts);
    gemm_kernel<<<(KN + 63) / 64, 256, 0, stream>>>(usb, meanb, counts, Wb, bself, bneigh, out);
}